// Round 1
// baseline (1048.629 us; speedup 1.0000x reference)
//
#include <hip/hip_runtime.h>
#include <hip/hip_bf16.h>

#define N_NODES 50000
#define N_EDGES 800000
#define DIM 128
#define N_LAYERS 4
#define SCAN_BLOCKS ((N_NODES + 1023) / 1024)
#define NSLOT 512

// ---------------- degree / CSR construction ----------------

__global__ void count_deg(const int* __restrict__ src, const int* __restrict__ dst,
                          int* __restrict__ deg_out, int* __restrict__ deg_in) {
    int e = blockIdx.x * blockDim.x + threadIdx.x;
    if (e < N_EDGES) {
        atomicAdd(&deg_out[src[e]], 1);
        atomicAdd(&deg_in[dst[e]], 1);
    }
}

__global__ void compute_dinv(const int* __restrict__ deg_in, float* __restrict__ dinv) {
    int i = blockIdx.x * blockDim.x + threadIdx.x;
    if (i < N_NODES) dinv[i] = rsqrtf((float)(deg_in[i] + 1));
}

__global__ void scan1(const int* __restrict__ deg_in, int* __restrict__ row_ptr,
                      int* __restrict__ aux) {
    __shared__ int s[1024];
    int t = threadIdx.x, b = blockIdx.x;
    int i = b * 1024 + t;
    int v = (i < N_NODES) ? deg_in[i] : 0;
    s[t] = v;
    __syncthreads();
    for (int off = 1; off < 1024; off <<= 1) {
        int x = (t >= off) ? s[t - off] : 0;
        __syncthreads();
        s[t] += x;
        __syncthreads();
    }
    if (i < N_NODES) row_ptr[i + 1] = s[t];
    if (t == 1023) aux[b] = s[1023];
}

__global__ void scan2(int* __restrict__ aux) {
    if (threadIdx.x == 0 && blockIdx.x == 0) {
        int run = 0;
        for (int b = 0; b < SCAN_BLOCKS; b++) { int x = aux[b]; aux[b] = run; run += x; }
    }
}

__global__ void scan3(int* __restrict__ row_ptr, const int* __restrict__ aux) {
    int t = threadIdx.x, b = blockIdx.x;
    int i = b * 1024 + t;
    if (i < N_NODES) row_ptr[i + 1] += aux[b];
    if (b == 0 && t == 0) row_ptr[0] = 0;
}

__global__ void fill_csr(const int* __restrict__ src, const int* __restrict__ dst,
                         const int* __restrict__ row_ptr, int* __restrict__ cursor,
                         const float* __restrict__ dinv, const int* __restrict__ deg_out,
                         int* __restrict__ csr_src, float* __restrict__ csr_norm,
                         float* __restrict__ csr_ew) {
    int e = blockIdx.x * blockDim.x + threadIdx.x;
    if (e >= N_EDGES) return;
    int s = src[e], d = dst[e];
    int pos = atomicAdd(&cursor[d], 1);
    int idx = row_ptr[d] + pos;
    csr_src[idx] = s;
    csr_norm[idx] = dinv[s] * dinv[d];
    csr_ew[idx] = 1.0f / (float)deg_out[s];
}

// ---------------- fp32 GEMM: C[M,128] = A[M,128] @ W[128,128]^T (+bias) ----------------
// 64x64 output tile per block, 256 threads, 4x4 register tile per thread.
// LDS: 64x128 f32 for A-tile and W-tile, XOR-swizzled in 16B blocks (no padding).

#define SWIDX(row, kb) (((row) << 7) + ((((kb) ^ ((row) & 7))) << 2))

__global__ __launch_bounds__(256) void gemm_tn(const float* __restrict__ A,
                                               const float* __restrict__ W,
                                               const float* __restrict__ bias,
                                               float* __restrict__ C, int M) {
    __shared__ float xs[64 * 128];
    __shared__ float ws[64 * 128];
    int t = threadIdx.x;
    int r0 = blockIdx.x * 64;
    int c0 = blockIdx.y * 64;

    // stage 64 rows x 128 floats of A and W, as float4
    for (int i = 0; i < 8; i++) {
        int f = t + (i << 8);
        int row = f >> 5;
        int kb = f & 31;
        int gr = r0 + row;
        float4 v = make_float4(0.f, 0.f, 0.f, 0.f);
        if (gr < M) v = ((const float4*)A)[gr * 32 + kb];
        *(float4*)&xs[SWIDX(row, kb)] = v;
        float4 wv = ((const float4*)W)[(c0 + row) * 32 + kb];
        *(float4*)&ws[SWIDX(row, kb)] = wv;
    }
    __syncthreads();

    int tc = t & 15;       // col thread
    int tr = t >> 4;       // row thread
    float acc[4][4] = {};

#pragma unroll 4
    for (int kb = 0; kb < 32; kb++) {
        float4 xa[4], wb[4];
#pragma unroll
        for (int i = 0; i < 4; i++) xa[i] = *(const float4*)&xs[SWIDX(tr + 16 * i, kb)];
#pragma unroll
        for (int j = 0; j < 4; j++) wb[j] = *(const float4*)&ws[SWIDX(tc + 16 * j, kb)];
#pragma unroll
        for (int i = 0; i < 4; i++)
#pragma unroll
            for (int j = 0; j < 4; j++) {
                acc[i][j] += xa[i].x * wb[j].x + xa[i].y * wb[j].y +
                             xa[i].z * wb[j].z + xa[i].w * wb[j].w;
            }
    }

    for (int i = 0; i < 4; i++) {
        int gr = r0 + tr + 16 * i;
        if (gr >= M) continue;
        for (int j = 0; j < 4; j++) {
            int gc = c0 + tc + 16 * j;
            float v = acc[i][j];
            if (bias) v += bias[gc];
            C[gr * DIM + gc] = v;
        }
    }
}

// ---------------- aggregation (scatter as per-node gather) + ReLU + norm ----------------

__global__ __launch_bounds__(128) void aggregate(const float* __restrict__ hw,
                                                 const int* __restrict__ row_ptr,
                                                 const int* __restrict__ csr_src,
                                                 const float* __restrict__ csr_norm,
                                                 const float* __restrict__ dinv,
                                                 float* __restrict__ h,
                                                 float* __restrict__ part_norm) {
    int d = blockIdx.x;
    int f = threadIdx.x;
    float di = dinv[d];
    float acc = di * di * hw[d * DIM + f];
    int e0 = row_ptr[d], e1 = row_ptr[d + 1];
    for (int e = e0; e < e1; e++) {
        int s = csr_src[e];
        float w = csr_norm[e];
        acc += w * hw[s * DIM + f];
    }
    float r = fmaxf(acc, 0.f);
    h[d * DIM + f] = r;
    float p = r * r;
    for (int off = 32; off > 0; off >>= 1) p += __shfl_down(p, off);
    __shared__ float sp[2];
    if ((f & 63) == 0) sp[f >> 6] = p;
    __syncthreads();
    if (f == 0) atomicAdd(&part_norm[d & (NSLOT - 1)], sp[0] + sp[1]);
}

// ---------------- Dirichlet energy over original edges (grouped by dst) ----------------

__global__ __launch_bounds__(128) void energy_k(const float* __restrict__ h,
                                                const int* __restrict__ row_ptr,
                                                const int* __restrict__ csr_src,
                                                const float* __restrict__ csr_ew,
                                                float* __restrict__ part_e) {
    int d = blockIdx.x;
    int f = threadIdx.x;
    float hd = h[d * DIM + f];
    int e0 = row_ptr[d], e1 = row_ptr[d + 1];
    float p = 0.f;
    for (int e = e0; e < e1; e++) {
        int s = csr_src[e];
        float ew = csr_ew[e];
        float diff = h[s * DIM + f] - hd;
        p += ew * diff * diff;
    }
    for (int off = 32; off > 0; off >>= 1) p += __shfl_down(p, off);
    __shared__ float sp[2];
    if ((f & 63) == 0) sp[f >> 6] = p;
    __syncthreads();
    if (f == 0) atomicAdd(&part_e[d & (NSLOT - 1)], 0.5f * (sp[0] + sp[1]));
}

// ---------------- final reduce of hashed partials into d_out ----------------

__global__ __launch_bounds__(512) void finalize(const float* __restrict__ part,
                                                float* __restrict__ out) {
    int o = blockIdx.x;
    int t = threadIdx.x;
    float p = part[o * NSLOT + t];
    for (int off = 32; off > 0; off >>= 1) p += __shfl_down(p, off);
    __shared__ float sp[8];
    if ((t & 63) == 0) sp[t >> 6] = p;
    __syncthreads();
    if (t == 0) {
        float s = 0.f;
        for (int i = 0; i < 8; i++) s += sp[i];
        out[o] = s;
    }
}

// ---------------- launch ----------------

extern "C" void kernel_launch(void* const* d_in, const int* in_sizes, int n_in,
                              void* d_out, int out_size, void* d_ws, size_t ws_size,
                              hipStream_t stream) {
    const float* x      = (const float*)d_in[0];
    const int*   ei     = (const int*)d_in[1];
    const float* enc_w  = (const float*)d_in[2];
    const float* enc_b  = (const float*)d_in[3];
    const float* convw  = (const float*)d_in[4];
    const int* src = ei;
    const int* dst = ei + N_EDGES;
    float* out = (float*)d_out;

    size_t off = 0;
    auto alloc = [&](size_t bytes) {
        void* p = (char*)d_ws + off;
        off += (bytes + 255) & ~(size_t)255;
        return p;
    };
    float* h        = (float*)alloc((size_t)N_NODES * DIM * 4);
    float* hw       = (float*)alloc((size_t)N_NODES * DIM * 4);
    int*   deg_out  = (int*)alloc((size_t)N_NODES * 4);
    int*   deg_in   = (int*)alloc((size_t)N_NODES * 4);
    float* dinv     = (float*)alloc((size_t)N_NODES * 4);
    int*   row_ptr  = (int*)alloc((size_t)(N_NODES + 1) * 4);
    int*   cursor   = (int*)alloc((size_t)N_NODES * 4);
    int*   aux      = (int*)alloc((size_t)(SCAN_BLOCKS + 1) * 4);
    int*   csr_src  = (int*)alloc((size_t)N_EDGES * 4);
    float* csr_norm = (float*)alloc((size_t)N_EDGES * 4);
    float* csr_ew   = (float*)alloc((size_t)N_EDGES * 4);
    float* part     = (float*)alloc((size_t)8 * NSLOT * 4);

    hipMemsetAsync(deg_out, 0, (size_t)N_NODES * 4, stream);
    hipMemsetAsync(deg_in, 0, (size_t)N_NODES * 4, stream);
    hipMemsetAsync(cursor, 0, (size_t)N_NODES * 4, stream);
    hipMemsetAsync(part, 0, (size_t)8 * NSLOT * 4, stream);

    int eb = (N_EDGES + 255) / 256;
    count_deg<<<eb, 256, 0, stream>>>(src, dst, deg_out, deg_in);
    compute_dinv<<<(N_NODES + 255) / 256, 256, 0, stream>>>(deg_in, dinv);
    scan1<<<SCAN_BLOCKS, 1024, 0, stream>>>(deg_in, row_ptr, aux);
    scan2<<<1, 64, 0, stream>>>(aux);
    scan3<<<SCAN_BLOCKS, 1024, 0, stream>>>(row_ptr, aux);
    fill_csr<<<eb, 256, 0, stream>>>(src, dst, row_ptr, cursor, dinv, deg_out,
                                     csr_src, csr_norm, csr_ew);

    dim3 ggrid((N_NODES + 63) / 64, 2);
    // encoder: h = x @ enc_w^T + enc_b
    gemm_tn<<<ggrid, 256, 0, stream>>>(x, enc_w, enc_b, h, N_NODES);

    for (int l = 0; l < N_LAYERS; l++) {
        const float* W = convw + (size_t)l * DIM * DIM;
        gemm_tn<<<ggrid, 256, 0, stream>>>(h, W, nullptr, hw, N_NODES);
        aggregate<<<N_NODES, 128, 0, stream>>>(hw, row_ptr, csr_src, csr_norm, dinv,
                                               h, part + (4 + l) * NSLOT);
        energy_k<<<N_NODES, 128, 0, stream>>>(h, row_ptr, csr_src, csr_ew,
                                              part + l * NSLOT);
    }
    finalize<<<8, NSLOT, 0, stream>>>(part, out);
}

// Round 2
// 588.492 us; speedup vs baseline: 1.7819x; 1.7819x over previous
//
#include <hip/hip_runtime.h>
#include <hip/hip_bf16.h>

#define N_NODES 50000
#define N_EDGES 800000
#define DIM 128
#define N_LAYERS 4
#define SCAN_BLOCKS ((N_NODES + 1023) / 1024)
#define NSLOT 512

typedef unsigned int uint;
typedef unsigned short ushort;

static __device__ __forceinline__ float bf2f_lo(uint w) { return __uint_as_float(w << 16); }
static __device__ __forceinline__ float bf2f_hi(uint w) { return __uint_as_float(w & 0xffff0000u); }
static __device__ __forceinline__ ushort f2bf(float f) {
    union { float f; uint u; } x; x.f = f;
    uint r = x.u + 0x7fffu + ((x.u >> 16) & 1u);   // RNE
    return (ushort)(r >> 16);
}

// ---------------- degree / CSR construction ----------------

__global__ void count_deg(const int* __restrict__ src, const int* __restrict__ dst,
                          int* __restrict__ deg_out, int* __restrict__ deg_in) {
    int e = blockIdx.x * blockDim.x + threadIdx.x;
    if (e < N_EDGES) {
        atomicAdd(&deg_out[src[e]], 1);
        atomicAdd(&deg_in[dst[e]], 1);
    }
}

__global__ void compute_dinv(const int* __restrict__ deg_in, float* __restrict__ dinv) {
    int i = blockIdx.x * blockDim.x + threadIdx.x;
    if (i < N_NODES) dinv[i] = rsqrtf((float)(deg_in[i] + 1));
}

__global__ void scan1(const int* __restrict__ deg_in, int* __restrict__ row_ptr,
                      int* __restrict__ aux) {
    __shared__ int s[1024];
    int t = threadIdx.x, b = blockIdx.x;
    int i = b * 1024 + t;
    int v = (i < N_NODES) ? deg_in[i] : 0;
    s[t] = v;
    __syncthreads();
    for (int off = 1; off < 1024; off <<= 1) {
        int x = (t >= off) ? s[t - off] : 0;
        __syncthreads();
        s[t] += x;
        __syncthreads();
    }
    if (i < N_NODES) row_ptr[i + 1] = s[t];
    if (t == 1023) aux[b] = s[1023];
}

__global__ void scan2(int* __restrict__ aux) {
    if (threadIdx.x == 0 && blockIdx.x == 0) {
        int run = 0;
        for (int b = 0; b < SCAN_BLOCKS; b++) { int x = aux[b]; aux[b] = run; run += x; }
    }
}

__global__ void scan3(int* __restrict__ row_ptr, const int* __restrict__ aux) {
    int t = threadIdx.x, b = blockIdx.x;
    int i = b * 1024 + t;
    if (i < N_NODES) row_ptr[i + 1] += aux[b];
    if (b == 0 && t == 0) row_ptr[0] = 0;
}

__global__ void fill_csr(const int* __restrict__ src, const int* __restrict__ dst,
                         const int* __restrict__ row_ptr, int* __restrict__ cursor,
                         const float* __restrict__ dinv, const int* __restrict__ deg_out,
                         int* __restrict__ csr_src, float* __restrict__ csr_norm,
                         float* __restrict__ csr_ew) {
    int e = blockIdx.x * blockDim.x + threadIdx.x;
    if (e >= N_EDGES) return;
    int s = src[e], d = dst[e];
    int pos = atomicAdd(&cursor[d], 1);
    int idx = row_ptr[d] + pos;
    csr_src[idx] = s;
    csr_norm[idx] = dinv[s] * dinv[d];
    csr_ew[idx] = 1.0f / (float)deg_out[s];
}

// ---------------- fused gather pass ----------------
// MODE bit0: aggregate  agg[d] = dinv[d]^2 * h[d] + sum_e norm_e * h[src_e]
// MODE bit1: energy     E += 0.5 * sum_e ew_e * ||h[src_e] - h[d]||^2
// One wave (64 lanes) per dst node; h is bf16, each lane holds 2 features (1 dword).

template <int MODE>
__global__ __launch_bounds__(256) void gather_pass(const ushort* __restrict__ h,
                                                   const int* __restrict__ row_ptr,
                                                   const int* __restrict__ csr_src,
                                                   const float* __restrict__ csr_norm,
                                                   const float* __restrict__ csr_ew,
                                                   const float* __restrict__ dinv,
                                                   float* __restrict__ agg,
                                                   float* __restrict__ part_e) {
    int wid = threadIdx.x >> 6;
    int lane = threadIdx.x & 63;
    int d = blockIdx.x * 4 + wid;
    if (d >= N_NODES) return;
    const uint* hu = (const uint*)h;               // 2 bf16 per dword, 64 dwords/row
    uint hdw = hu[d * 64 + lane];
    float hd0 = bf2f_lo(hdw), hd1 = bf2f_hi(hdw);
    float a0 = 0.f, a1 = 0.f;
    if (MODE & 1) { float di = dinv[d]; float w = di * di; a0 = w * hd0; a1 = w * hd1; }
    float ep = 0.f;
    int e0 = row_ptr[d], e1 = row_ptr[d + 1];
    int e = e0;
    for (; e + 1 < e1; e += 2) {                   // 2-deep for MLP
        int s0 = csr_src[e], s1 = csr_src[e + 1];
        uint v0 = hu[s0 * 64 + lane];
        uint v1 = hu[s1 * 64 + lane];
        float x0 = bf2f_lo(v0), x1 = bf2f_hi(v0);
        float y0 = bf2f_lo(v1), y1 = bf2f_hi(v1);
        if (MODE & 1) {
            float w0 = csr_norm[e], w1 = csr_norm[e + 1];
            a0 += w0 * x0 + w1 * y0;
            a1 += w0 * x1 + w1 * y1;
        }
        if (MODE & 2) {
            float ew0 = csr_ew[e], ew1 = csr_ew[e + 1];
            float dx0 = x0 - hd0, dx1 = x1 - hd1;
            float dy0 = y0 - hd0, dy1 = y1 - hd1;
            ep += ew0 * (dx0 * dx0 + dx1 * dx1) + ew1 * (dy0 * dy0 + dy1 * dy1);
        }
    }
    if (e < e1) {
        int s0 = csr_src[e];
        uint v0 = hu[s0 * 64 + lane];
        float x0 = bf2f_lo(v0), x1 = bf2f_hi(v0);
        if (MODE & 1) { float w0 = csr_norm[e]; a0 += w0 * x0; a1 += w0 * x1; }
        if (MODE & 2) {
            float ew0 = csr_ew[e];
            float dx0 = x0 - hd0, dx1 = x1 - hd1;
            ep += ew0 * (dx0 * dx0 + dx1 * dx1);
        }
    }
    if (MODE & 1) ((float2*)agg)[d * 64 + lane] = make_float2(a0, a1);
    if (MODE & 2) {
        for (int off = 32; off > 0; off >>= 1) ep += __shfl_down(ep, off);
        if (lane == 0) atomicAdd(&part_e[d & (NSLOT - 1)], 0.5f * ep);
    }
}

// ---------------- fp32 GEMM: C[M,128] = A[M,128] @ W[128,128]^T, fused epilogue ----------
// 64x64 tile / block, 256 threads, 4x4 register tile. Epilogue: +bias / relu / bf16 store /
// sum of squares accumulation into hashed partials.

#define SWIDX(row, kb) (((row) << 7) + ((((kb) ^ ((row) & 7))) << 2))

template <bool RELU, bool NORM, bool BIAS>
__global__ __launch_bounds__(256) void gemm_ep(const float* __restrict__ A,
                                               const float* __restrict__ W,
                                               const float* __restrict__ bias,
                                               ushort* __restrict__ Cb, int M,
                                               float* __restrict__ part_norm) {
    __shared__ float xs[64 * 128];
    __shared__ float ws[64 * 128];
    int t = threadIdx.x;
    int r0 = blockIdx.x * 64;
    int c0 = blockIdx.y * 64;

    for (int i = 0; i < 8; i++) {
        int f = t + (i << 8);
        int row = f >> 5;
        int kb = f & 31;
        int gr = r0 + row;
        float4 v = make_float4(0.f, 0.f, 0.f, 0.f);
        if (gr < M) v = ((const float4*)A)[gr * 32 + kb];
        *(float4*)&xs[SWIDX(row, kb)] = v;
        float4 wv = ((const float4*)W)[(c0 + row) * 32 + kb];
        *(float4*)&ws[SWIDX(row, kb)] = wv;
    }
    __syncthreads();

    int tc = t & 15;
    int tr = t >> 4;
    float acc[4][4] = {};

#pragma unroll 4
    for (int kb = 0; kb < 32; kb++) {
        float4 xa[4], wb[4];
#pragma unroll
        for (int i = 0; i < 4; i++) xa[i] = *(const float4*)&xs[SWIDX(tr + 16 * i, kb)];
#pragma unroll
        for (int j = 0; j < 4; j++) wb[j] = *(const float4*)&ws[SWIDX(tc + 16 * j, kb)];
#pragma unroll
        for (int i = 0; i < 4; i++)
#pragma unroll
            for (int j = 0; j < 4; j++) {
                acc[i][j] += xa[i].x * wb[j].x + xa[i].y * wb[j].y +
                             xa[i].z * wb[j].z + xa[i].w * wb[j].w;
            }
    }

    float p = 0.f;
    for (int i = 0; i < 4; i++) {
        int gr = r0 + tr + 16 * i;
        if (gr >= M) continue;
        for (int j = 0; j < 4; j++) {
            int gc = c0 + tc + 16 * j;
            float v = acc[i][j];
            if (BIAS) v += bias[gc];
            if (RELU) v = fmaxf(v, 0.f);
            if (NORM) p += v * v;
            Cb[gr * DIM + gc] = f2bf(v);
        }
    }
    if (NORM) {
        for (int off = 32; off > 0; off >>= 1) p += __shfl_down(p, off);
        __shared__ float sp[4];
        if ((t & 63) == 0) sp[t >> 6] = p;
        __syncthreads();
        if (t == 0) {
            float s = sp[0] + sp[1] + sp[2] + sp[3];
            int slot = (blockIdx.x + blockIdx.y * gridDim.x) & (NSLOT - 1);
            atomicAdd(&part_norm[slot], s);
        }
    }
}

// ---------------- final reduce of hashed partials into d_out ----------------

__global__ __launch_bounds__(512) void finalize(const float* __restrict__ part,
                                                float* __restrict__ out) {
    int o = blockIdx.x;
    int t = threadIdx.x;
    float p = part[o * NSLOT + t];
    for (int off = 32; off > 0; off >>= 1) p += __shfl_down(p, off);
    __shared__ float sp[8];
    if ((t & 63) == 0) sp[t >> 6] = p;
    __syncthreads();
    if (t == 0) {
        float s = 0.f;
        for (int i = 0; i < 8; i++) s += sp[i];
        out[o] = s;
    }
}

// ---------------- launch ----------------

extern "C" void kernel_launch(void* const* d_in, const int* in_sizes, int n_in,
                              void* d_out, int out_size, void* d_ws, size_t ws_size,
                              hipStream_t stream) {
    const float* x      = (const float*)d_in[0];
    const int*   ei     = (const int*)d_in[1];
    const float* enc_w  = (const float*)d_in[2];
    const float* enc_b  = (const float*)d_in[3];
    const float* convw  = (const float*)d_in[4];
    const int* src = ei;
    const int* dst = ei + N_EDGES;
    float* out = (float*)d_out;

    size_t off = 0;
    auto alloc = [&](size_t bytes) {
        void* p = (char*)d_ws + off;
        off += (bytes + 255) & ~(size_t)255;
        return p;
    };
    ushort* h       = (ushort*)alloc((size_t)N_NODES * DIM * 2);   // bf16 features
    float* agg      = (float*)alloc((size_t)N_NODES * DIM * 4);    // fp32 aggregate
    int*   deg_out  = (int*)alloc((size_t)N_NODES * 4);
    int*   deg_in   = (int*)alloc((size_t)N_NODES * 4);
    float* dinv     = (float*)alloc((size_t)N_NODES * 4);
    int*   row_ptr  = (int*)alloc((size_t)(N_NODES + 1) * 4);
    int*   cursor   = (int*)alloc((size_t)N_NODES * 4);
    int*   aux      = (int*)alloc((size_t)(SCAN_BLOCKS + 1) * 4);
    int*   csr_src  = (int*)alloc((size_t)N_EDGES * 4);
    float* csr_norm = (float*)alloc((size_t)N_EDGES * 4);
    float* csr_ew   = (float*)alloc((size_t)N_EDGES * 4);
    float* part     = (float*)alloc((size_t)8 * NSLOT * 4);

    hipMemsetAsync(deg_out, 0, (size_t)N_NODES * 4, stream);
    hipMemsetAsync(deg_in, 0, (size_t)N_NODES * 4, stream);
    hipMemsetAsync(cursor, 0, (size_t)N_NODES * 4, stream);
    hipMemsetAsync(part, 0, (size_t)8 * NSLOT * 4, stream);

    int eb = (N_EDGES + 255) / 256;
    count_deg<<<eb, 256, 0, stream>>>(src, dst, deg_out, deg_in);
    compute_dinv<<<(N_NODES + 255) / 256, 256, 0, stream>>>(deg_in, dinv);
    scan1<<<SCAN_BLOCKS, 1024, 0, stream>>>(deg_in, row_ptr, aux);
    scan2<<<1, 64, 0, stream>>>(aux);
    scan3<<<SCAN_BLOCKS, 1024, 0, stream>>>(row_ptr, aux);
    fill_csr<<<eb, 256, 0, stream>>>(src, dst, row_ptr, cursor, dinv, deg_out,
                                     csr_src, csr_norm, csr_ew);

    dim3 ggrid((N_NODES + 63) / 64, 2);
    int gb = (N_NODES + 3) / 4;

    // encoder: h0 = x @ enc_w^T + enc_b   (bf16 out, no relu, no norm)
    gemm_ep<false, false, true><<<ggrid, 256, 0, stream>>>(x, enc_w, enc_b, h, N_NODES, nullptr);

    // layer 1: agg1 (no energy yet)
    gather_pass<1><<<gb, 256, 0, stream>>>(h, row_ptr, csr_src, csr_norm, csr_ew, dinv,
                                           agg, nullptr);
    gemm_ep<true, true, false><<<ggrid, 256, 0, stream>>>(agg, convw + 0 * DIM * DIM, nullptr,
                                                          h, N_NODES, part + 4 * NSLOT);
    // layers 2..4: fused agg(l) + energy(l-1)
    for (int l = 1; l < N_LAYERS; l++) {
        gather_pass<3><<<gb, 256, 0, stream>>>(h, row_ptr, csr_src, csr_norm, csr_ew, dinv,
                                               agg, part + (l - 1) * NSLOT);
        gemm_ep<true, true, false><<<ggrid, 256, 0, stream>>>(agg, convw + (size_t)l * DIM * DIM,
                                                              nullptr, h, N_NODES,
                                                              part + (4 + l) * NSLOT);
    }
    // final: energy(4) only
    gather_pass<2><<<gb, 256, 0, stream>>>(h, row_ptr, csr_src, csr_norm, csr_ew, dinv,
                                           nullptr, part + 3 * NSLOT);
    finalize<<<8, NSLOT, 0, stream>>>(part, out);
}

// Round 3
// 427.155 us; speedup vs baseline: 2.4549x; 1.3777x over previous
//
#include <hip/hip_runtime.h>
#include <hip/hip_bf16.h>

#define N_NODES 50000
#define N_EDGES 800000
#define DIM 128
#define N_LAYERS 4
#define SCAN_BLOCKS ((N_NODES + 1023) / 1024)
#define NSLOT 512
#define NTILES (N_NODES / 16)   // 3125, exact

typedef unsigned int uint;
typedef unsigned short ushort;
typedef __attribute__((ext_vector_type(8))) short short8;
typedef __attribute__((ext_vector_type(4))) float f32x4;

static __device__ __forceinline__ float bf2f_lo(uint w) { return __uint_as_float(w << 16); }
static __device__ __forceinline__ float bf2f_hi(uint w) { return __uint_as_float(w & 0xffff0000u); }
static __device__ __forceinline__ ushort f2bf(float f) {
    union { float f; uint u; } x; x.f = f;
    uint r = x.u + 0x7fffu + ((x.u >> 16) & 1u);   // RNE
    return (ushort)(r >> 16);
}

// ---------------- degree / CSR construction ----------------

__global__ void count_deg(const int* __restrict__ src, const int* __restrict__ dst,
                          int* __restrict__ deg_out, int* __restrict__ deg_in) {
    int e = blockIdx.x * blockDim.x + threadIdx.x;
    if (e < N_EDGES) {
        atomicAdd(&deg_out[src[e]], 1);
        atomicAdd(&deg_in[dst[e]], 1);
    }
}

__global__ void compute_dinv(const int* __restrict__ deg_in, float* __restrict__ dinv) {
    int i = blockIdx.x * blockDim.x + threadIdx.x;
    if (i < N_NODES) dinv[i] = rsqrtf((float)(deg_in[i] + 1));
}

__global__ void scan1(const int* __restrict__ deg_in, int* __restrict__ row_ptr,
                      int* __restrict__ aux) {
    __shared__ int s[1024];
    int t = threadIdx.x, b = blockIdx.x;
    int i = b * 1024 + t;
    int v = (i < N_NODES) ? deg_in[i] : 0;
    s[t] = v;
    __syncthreads();
    for (int off = 1; off < 1024; off <<= 1) {
        int x = (t >= off) ? s[t - off] : 0;
        __syncthreads();
        s[t] += x;
        __syncthreads();
    }
    if (i < N_NODES) row_ptr[i + 1] = s[t];
    if (t == 1023) aux[b] = s[1023];
}

__global__ void scan2(int* __restrict__ aux) {
    if (threadIdx.x == 0 && blockIdx.x == 0) {
        int run = 0;
        for (int b = 0; b < SCAN_BLOCKS; b++) { int x = aux[b]; aux[b] = run; run += x; }
    }
}

__global__ void scan3(int* __restrict__ row_ptr, const int* __restrict__ aux) {
    int t = threadIdx.x, b = blockIdx.x;
    int i = b * 1024 + t;
    if (i < N_NODES) row_ptr[i + 1] += aux[b];
    if (b == 0 && t == 0) row_ptr[0] = 0;
}

// meta per CSR slot: {src*256 (byte offset), bits(norm), bits(ew), 0}
__global__ void fill_csr(const int* __restrict__ src, const int* __restrict__ dst,
                         const int* __restrict__ row_ptr, int* __restrict__ cursor,
                         const float* __restrict__ dinv, const int* __restrict__ deg_out,
                         int4* __restrict__ meta) {
    int e = blockIdx.x * blockDim.x + threadIdx.x;
    if (e >= N_EDGES) return;
    int s = src[e], d = dst[e];
    int pos = atomicAdd(&cursor[d], 1);
    int idx = row_ptr[d] + pos;
    meta[idx] = make_int4(s << 8,
                          __float_as_int(dinv[s] * dinv[d]),
                          __float_as_int(1.0f / (float)deg_out[s]), 0);
}

// ---------------- weights fp32 -> bf16 (once) ----------------

__global__ void cvt_w(const float* __restrict__ enc_w, const float* __restrict__ convw,
                      ushort* __restrict__ wsb) {
    int i = blockIdx.x * 256 + threadIdx.x;
    if (i < DIM * DIM) wsb[i] = f2bf(enc_w[i]);
    else if (i < 5 * DIM * DIM) wsb[i] = f2bf(convw[i - DIM * DIM]);
}

// ---------------- MFMA GEMM: C[M,128] = A[M,128] @ W[128,128]^T ----------------
// Persistent waves; whole W held in 32 register fragments per wave (no LDS).
// mfma_f32_16x16x32_bf16: A/B lane l -> row l&15, k = 8*(l>>4)+j (16B contiguous);
// C/D lane l -> col l&15, row 4*(l>>4)+i  [verified m89/m91 mapping].

template <bool AFP32, bool RELU, bool NORM, bool BIAS>
__global__ __launch_bounds__(256) void gemm_mfma(const void* __restrict__ Av,
                                                 const ushort* __restrict__ Wb,
                                                 const float* __restrict__ bias,
                                                 ushort* __restrict__ Cb,
                                                 float* __restrict__ part_norm) {
    int lane = threadIdx.x & 63;
    int wid  = threadIdx.x >> 6;
    int lr = lane & 15;
    int lk = lane >> 4;

    short8 wf[8][4];
#pragma unroll
    for (int jt = 0; jt < 8; jt++)
#pragma unroll
        for (int kt = 0; kt < 4; kt++)
            wf[jt][kt] = *(const short8*)&Wb[(jt * 16 + lr) * DIM + kt * 32 + lk * 8];

    float breg[8];
    if constexpr (BIAS) {
#pragma unroll
        for (int jt = 0; jt < 8; jt++) breg[jt] = bias[jt * 16 + lr];
    }

    int wglobal = blockIdx.x * 4 + wid;
    int wstride = gridDim.x * 4;
    float pn = 0.f;

    auto load_a = [&](int tile, short8* a) {
        int row = tile * 16 + lr;
        if constexpr (AFP32) {
            const float* A = (const float*)Av;
#pragma unroll
            for (int kt = 0; kt < 4; kt++) {
                const float* p = &A[row * DIM + kt * 32 + lk * 8];
                float4 v0 = *(const float4*)p;
                float4 v1 = *(const float4*)(p + 4);
                short8 s;
                s[0] = (short)f2bf(v0.x); s[1] = (short)f2bf(v0.y);
                s[2] = (short)f2bf(v0.z); s[3] = (short)f2bf(v0.w);
                s[4] = (short)f2bf(v1.x); s[5] = (short)f2bf(v1.y);
                s[6] = (short)f2bf(v1.z); s[7] = (short)f2bf(v1.w);
                a[kt] = s;
            }
        } else {
            const ushort* A = (const ushort*)Av;
#pragma unroll
            for (int kt = 0; kt < 4; kt++)
                a[kt] = *(const short8*)&A[row * DIM + kt * 32 + lk * 8];
        }
    };

    short8 aA[4], aB[4];
    int tile = wglobal;
    if (tile < NTILES) load_a(tile, aA);
    while (tile < NTILES) {
        int nxt = tile + wstride;
        if (nxt < NTILES) load_a(nxt, aB);   // prefetch next row-tile

        f32x4 acc[8];
#pragma unroll
        for (int jt = 0; jt < 8; jt++) { f32x4 z = {0.f, 0.f, 0.f, 0.f}; acc[jt] = z; }
#pragma unroll
        for (int kt = 0; kt < 4; kt++)
#pragma unroll
            for (int jt = 0; jt < 8; jt++)
                acc[jt] = __builtin_amdgcn_mfma_f32_16x16x32_bf16(aA[kt], wf[jt][kt],
                                                                  acc[jt], 0, 0, 0);
#pragma unroll
        for (int jt = 0; jt < 8; jt++) {
#pragma unroll
            for (int i = 0; i < 4; i++) {
                float v = acc[jt][i];
                if constexpr (BIAS) v += breg[jt];
                if constexpr (RELU) v = fmaxf(v, 0.f);
                if constexpr (NORM) pn += v * v;
                int row = tile * 16 + lk * 4 + i;
                Cb[row * DIM + jt * 16 + lr] = f2bf(v);
            }
        }
#pragma unroll
        for (int kt = 0; kt < 4; kt++) aA[kt] = aB[kt];
        tile = nxt;
    }
    if constexpr (NORM) {
        for (int off = 32; off > 0; off >>= 1) pn += __shfl_down(pn, off);
        if (lane == 0) atomicAdd(&part_norm[(blockIdx.x * 4 + wid) & (NSLOT - 1)], pn);
    }
}

// ---------------- fused gather pass ----------------
// MODE bit0: aggregate  aggb[d] = dinv[d]^2*h[d] + sum_e norm_e*h[src_e]  (bf16 out)
// MODE bit1: energy     E += 0.5*sum_e ew_e*||h[src_e]-h[d]||^2
// One wave per dst node; h bf16, 2 features per lane per dword.

template <int MODE>
__global__ __launch_bounds__(256) void gather_pass(const ushort* __restrict__ h,
                                                   const int* __restrict__ row_ptr,
                                                   const int4* __restrict__ meta,
                                                   const float* __restrict__ dinv,
                                                   uint* __restrict__ aggb,
                                                   float* __restrict__ part_e) {
    int wid = threadIdx.x >> 6;
    int lane = threadIdx.x & 63;
    int d = blockIdx.x * 4 + wid;
    if (d >= N_NODES) return;
    const char* hb = (const char*)h;
    int lane4 = lane * 4;
    uint hdw = *(const uint*)(hb + (size_t)d * 256 + lane4);
    float hd0 = bf2f_lo(hdw), hd1 = bf2f_hi(hdw);
    float a0 = 0.f, a1 = 0.f;
    if (MODE & 1) { float di = dinv[d]; float w = di * di; a0 = w * hd0; a1 = w * hd1; }
    float ep = 0.f;

    auto body = [&](int4 m) {
        uint v = *(const uint*)(hb + (size_t)(uint)(m.x + lane4));
        float x0 = bf2f_lo(v), x1 = bf2f_hi(v);
        if (MODE & 1) {
            float w = __int_as_float(m.y);
            a0 += w * x0; a1 += w * x1;
        }
        if (MODE & 2) {
            float ew = __int_as_float(m.z);
            float dx0 = x0 - hd0, dx1 = x1 - hd1;
            ep += ew * (dx0 * dx0 + dx1 * dx1);
        }
    };

    int e0 = row_ptr[d], e1 = row_ptr[d + 1];
    int e = e0;
    for (; e + 3 < e1; e += 4) {
        int4 m0 = meta[e], m1 = meta[e + 1], m2 = meta[e + 2], m3 = meta[e + 3];
        body(m0); body(m1); body(m2); body(m3);
    }
    for (; e < e1; e++) body(meta[e]);

    if (MODE & 1) {
        uint pk = (uint)f2bf(a0) | ((uint)f2bf(a1) << 16);
        aggb[(size_t)d * 64 + lane] = pk;
    }
    if (MODE & 2) {
        for (int off = 32; off > 0; off >>= 1) ep += __shfl_down(ep, off);
        if (lane == 0) atomicAdd(&part_e[d & (NSLOT - 1)], 0.5f * ep);
    }
}

// ---------------- final reduce ----------------

__global__ __launch_bounds__(512) void finalize(const float* __restrict__ part,
                                                float* __restrict__ out) {
    int o = blockIdx.x;
    int t = threadIdx.x;
    float p = part[o * NSLOT + t];
    for (int off = 32; off > 0; off >>= 1) p += __shfl_down(p, off);
    __shared__ float sp[8];
    if ((t & 63) == 0) sp[t >> 6] = p;
    __syncthreads();
    if (t == 0) {
        float s = 0.f;
        for (int i = 0; i < 8; i++) s += sp[i];
        out[o] = s;
    }
}

// ---------------- launch ----------------

extern "C" void kernel_launch(void* const* d_in, const int* in_sizes, int n_in,
                              void* d_out, int out_size, void* d_ws, size_t ws_size,
                              hipStream_t stream) {
    const float* x      = (const float*)d_in[0];
    const int*   ei     = (const int*)d_in[1];
    const float* enc_w  = (const float*)d_in[2];
    const float* enc_b  = (const float*)d_in[3];
    const float* convw  = (const float*)d_in[4];
    const int* src = ei;
    const int* dst = ei + N_EDGES;
    float* out = (float*)d_out;

    size_t off = 0;
    auto alloc = [&](size_t bytes) {
        void* p = (char*)d_ws + off;
        off += (bytes + 255) & ~(size_t)255;
        return p;
    };
    ushort* h       = (ushort*)alloc((size_t)N_NODES * DIM * 2);   // bf16 features
    uint*   aggb    = (uint*)alloc((size_t)N_NODES * DIM * 2);     // bf16 aggregate
    ushort* wsb     = (ushort*)alloc((size_t)5 * DIM * DIM * 2);   // bf16 weights
    int*   deg_out  = (int*)alloc((size_t)N_NODES * 4);
    int*   deg_in   = (int*)alloc((size_t)N_NODES * 4);
    float* dinv     = (float*)alloc((size_t)N_NODES * 4);
    int*   row_ptr  = (int*)alloc((size_t)(N_NODES + 1) * 4);
    int*   cursor   = (int*)alloc((size_t)N_NODES * 4);
    int*   aux      = (int*)alloc((size_t)(SCAN_BLOCKS + 1) * 4);
    int4*  meta     = (int4*)alloc((size_t)N_EDGES * 16);
    float* part     = (float*)alloc((size_t)8 * NSLOT * 4);

    hipMemsetAsync(deg_out, 0, (size_t)N_NODES * 4, stream);
    hipMemsetAsync(deg_in, 0, (size_t)N_NODES * 4, stream);
    hipMemsetAsync(cursor, 0, (size_t)N_NODES * 4, stream);
    hipMemsetAsync(part, 0, (size_t)8 * NSLOT * 4, stream);

    int eb = (N_EDGES + 255) / 256;
    cvt_w<<<(5 * DIM * DIM + 255) / 256, 256, 0, stream>>>(enc_w, convw, wsb);
    count_deg<<<eb, 256, 0, stream>>>(src, dst, deg_out, deg_in);
    compute_dinv<<<(N_NODES + 255) / 256, 256, 0, stream>>>(deg_in, dinv);
    scan1<<<SCAN_BLOCKS, 1024, 0, stream>>>(deg_in, row_ptr, aux);
    scan2<<<1, 64, 0, stream>>>(aux);
    scan3<<<SCAN_BLOCKS, 1024, 0, stream>>>(row_ptr, aux);
    fill_csr<<<eb, 256, 0, stream>>>(src, dst, row_ptr, cursor, dinv, deg_out, meta);

    int gb = (N_NODES + 3) / 4;
    const int GB = 256;   // GEMM blocks (persistent waves)

    // encoder: h0 = x @ enc_w^T + enc_b
    gemm_mfma<true, false, false, true><<<GB, 256, 0, stream>>>(x, wsb, enc_b, h, nullptr);

    // layer 1: agg only
    gather_pass<1><<<gb, 256, 0, stream>>>(h, row_ptr, meta, dinv, aggb, nullptr);
    gemm_mfma<false, true, true, false><<<GB, 256, 0, stream>>>(aggb, wsb + DIM * DIM, nullptr,
                                                                h, part + 4 * NSLOT);
    // layers 2..4: fused agg(l) + energy(l-1)
    for (int l = 1; l < N_LAYERS; l++) {
        gather_pass<3><<<gb, 256, 0, stream>>>(h, row_ptr, meta, dinv, aggb,
                                               part + (l - 1) * NSLOT);
        gemm_mfma<false, true, true, false><<<GB, 256, 0, stream>>>(
            aggb, wsb + (size_t)(1 + l) * DIM * DIM, nullptr, h, part + (4 + l) * NSLOT);
    }
    // final: energy(4) only
    gather_pass<2><<<gb, 256, 0, stream>>>(h, row_ptr, meta, dinv, nullptr,
                                           part + 3 * NSLOT);
    finalize<<<8, NSLOT, 0, stream>>>(part, out);
}

// Round 4
// 401.986 us; speedup vs baseline: 2.6086x; 1.0626x over previous
//
#include <hip/hip_runtime.h>
#include <hip/hip_bf16.h>

#define N_NODES 50000
#define N_EDGES 800000
#define DIM 128
#define N_LAYERS 4
#define SCAN_BLOCKS ((N_NODES + 1023) / 1024)
#define NSLOT 512
#define NTILES (N_NODES / 16)   // 3125, exact

typedef unsigned int uint;
typedef unsigned short ushort;
typedef __attribute__((ext_vector_type(8))) short short8;
typedef __attribute__((ext_vector_type(4))) float f32x4;

static __device__ __forceinline__ float bf2f_lo(uint w) { return __uint_as_float(w << 16); }
static __device__ __forceinline__ float bf2f_hi(uint w) { return __uint_as_float(w & 0xffff0000u); }
static __device__ __forceinline__ ushort f2bf(float f) {
    union { float f; uint u; } x; x.f = f;
    uint r = x.u + 0x7fffu + ((x.u >> 16) & 1u);   // RNE
    return (ushort)(r >> 16);
}

// ---------------- degree / CSR construction ----------------

__global__ void count_deg(const int* __restrict__ src, const int* __restrict__ dst,
                          int* __restrict__ deg_out, int* __restrict__ deg_in) {
    int e = blockIdx.x * blockDim.x + threadIdx.x;
    if (e < N_EDGES) {
        atomicAdd(&deg_out[src[e]], 1);
        atomicAdd(&deg_in[dst[e]], 1);
    }
}

// np[i] = {dinv_i, 1/deg_out_i}
__global__ void compute_nodeprops(const int* __restrict__ deg_in,
                                  const int* __restrict__ deg_out,
                                  float* __restrict__ dinv, float2* __restrict__ np) {
    int i = blockIdx.x * blockDim.x + threadIdx.x;
    if (i < N_NODES) {
        float di = rsqrtf((float)(deg_in[i] + 1));
        dinv[i] = di;
        np[i] = make_float2(di, 1.0f / (float)deg_out[i]);
    }
}

__global__ void scan1(const int* __restrict__ deg_in, int* __restrict__ row_ptr,
                      int* __restrict__ aux) {
    __shared__ int s[1024];
    int t = threadIdx.x, b = blockIdx.x;
    int i = b * 1024 + t;
    int v = (i < N_NODES) ? deg_in[i] : 0;
    s[t] = v;
    __syncthreads();
    for (int off = 1; off < 1024; off <<= 1) {
        int x = (t >= off) ? s[t - off] : 0;
        __syncthreads();
        s[t] += x;
        __syncthreads();
    }
    if (i < N_NODES) row_ptr[i + 1] = s[t];
    if (t == 1023) aux[b] = s[1023];
}

__global__ void scan2(int* __restrict__ aux) {
    if (threadIdx.x == 0 && blockIdx.x == 0) {
        int run = 0;
        for (int b = 0; b < SCAN_BLOCKS; b++) { int x = aux[b]; aux[b] = run; run += x; }
    }
}

__global__ void scan3(int* __restrict__ row_ptr, const int* __restrict__ aux) {
    int t = threadIdx.x, b = blockIdx.x;
    int i = b * 1024 + t;
    if (i < N_NODES) row_ptr[i + 1] += aux[b];
    if (b == 0 && t == 0) row_ptr[0] = 0;
}

// meta per CSR slot (8B): {src*256 byte-offset, packed(norm_bf16 lo, ew_bf16 hi)}
__global__ void fill_csr(const int* __restrict__ src, const int* __restrict__ dst,
                         const int* __restrict__ row_ptr, int* __restrict__ cursor,
                         const float* __restrict__ dinv, const float2* __restrict__ np,
                         int2* __restrict__ meta) {
    int e = blockIdx.x * blockDim.x + threadIdx.x;
    if (e >= N_EDGES) return;
    int s = src[e], d = dst[e];
    float2 ns = np[s];
    float dd = dinv[d];
    int pos = atomicAdd(&cursor[d], 1);
    int idx = row_ptr[d] + pos;
    uint pk = (uint)f2bf(ns.x * dd) | ((uint)f2bf(ns.y) << 16);
    meta[idx] = make_int2(s << 8, (int)pk);
}

// ---------------- weights fp32 -> bf16 (once) ----------------

__global__ void cvt_w(const float* __restrict__ enc_w, const float* __restrict__ convw,
                      ushort* __restrict__ wsb) {
    int i = blockIdx.x * 256 + threadIdx.x;
    if (i < DIM * DIM) wsb[i] = f2bf(enc_w[i]);
    else if (i < 5 * DIM * DIM) wsb[i] = f2bf(convw[i - DIM * DIM]);
}

// ---------------- MFMA GEMM: C[M,128] = A[M,128] @ W[128,128]^T ----------------
// Persistent waves; whole W held in 32 register fragments per wave (no LDS).

template <bool AFP32, bool RELU, bool NORM, bool BIAS>
__global__ __launch_bounds__(256) void gemm_mfma(const void* __restrict__ Av,
                                                 const ushort* __restrict__ Wb,
                                                 const float* __restrict__ bias,
                                                 ushort* __restrict__ Cb,
                                                 float* __restrict__ part_norm) {
    int lane = threadIdx.x & 63;
    int wid  = threadIdx.x >> 6;
    int lr = lane & 15;
    int lk = lane >> 4;

    short8 wf[8][4];
#pragma unroll
    for (int jt = 0; jt < 8; jt++)
#pragma unroll
        for (int kt = 0; kt < 4; kt++)
            wf[jt][kt] = *(const short8*)&Wb[(jt * 16 + lr) * DIM + kt * 32 + lk * 8];

    float breg[8];
    if constexpr (BIAS) {
#pragma unroll
        for (int jt = 0; jt < 8; jt++) breg[jt] = bias[jt * 16 + lr];
    }

    int wglobal = blockIdx.x * 4 + wid;
    int wstride = gridDim.x * 4;
    float pn = 0.f;

    auto load_a = [&](int tile, short8* a) {
        int row = tile * 16 + lr;
        if constexpr (AFP32) {
            const float* A = (const float*)Av;
#pragma unroll
            for (int kt = 0; kt < 4; kt++) {
                const float* p = &A[row * DIM + kt * 32 + lk * 8];
                float4 v0 = *(const float4*)p;
                float4 v1 = *(const float4*)(p + 4);
                short8 s;
                s[0] = (short)f2bf(v0.x); s[1] = (short)f2bf(v0.y);
                s[2] = (short)f2bf(v0.z); s[3] = (short)f2bf(v0.w);
                s[4] = (short)f2bf(v1.x); s[5] = (short)f2bf(v1.y);
                s[6] = (short)f2bf(v1.z); s[7] = (short)f2bf(v1.w);
                a[kt] = s;
            }
        } else {
            const ushort* A = (const ushort*)Av;
#pragma unroll
            for (int kt = 0; kt < 4; kt++)
                a[kt] = *(const short8*)&A[row * DIM + kt * 32 + lk * 8];
        }
    };

    short8 aA[4], aB[4];
    int tile = wglobal;
    if (tile < NTILES) load_a(tile, aA);
    while (tile < NTILES) {
        int nxt = tile + wstride;
        if (nxt < NTILES) load_a(nxt, aB);   // prefetch next row-tile

        f32x4 acc[8];
#pragma unroll
        for (int jt = 0; jt < 8; jt++) { f32x4 z = {0.f, 0.f, 0.f, 0.f}; acc[jt] = z; }
#pragma unroll
        for (int kt = 0; kt < 4; kt++)
#pragma unroll
            for (int jt = 0; jt < 8; jt++)
                acc[jt] = __builtin_amdgcn_mfma_f32_16x16x32_bf16(aA[kt], wf[jt][kt],
                                                                  acc[jt], 0, 0, 0);
#pragma unroll
        for (int jt = 0; jt < 8; jt++) {
#pragma unroll
            for (int i = 0; i < 4; i++) {
                float v = acc[jt][i];
                if constexpr (BIAS) v += breg[jt];
                if constexpr (RELU) v = fmaxf(v, 0.f);
                if constexpr (NORM) pn += v * v;
                int row = tile * 16 + lk * 4 + i;
                Cb[row * DIM + jt * 16 + lr] = f2bf(v);
            }
        }
#pragma unroll
        for (int kt = 0; kt < 4; kt++) aA[kt] = aB[kt];
        tile = nxt;
    }
    if constexpr (NORM) {
        for (int off = 32; off > 0; off >>= 1) pn += __shfl_down(pn, off);
        if (lane == 0) atomicAdd(&part_norm[(blockIdx.x * 4 + wid) & (NSLOT - 1)], pn);
    }
}

// ---------------- fused gather pass ----------------
// MODE bit0: aggregate  aggb[d] = dinv[d]^2*h[d] + sum_e norm_e*h[src_e]  (bf16 out)
// MODE bit1: energy     E += 0.5*sum_e ew_e*||h[src_e]-h[d]||^2
// One wave per dst node. Edge meta lane-parallel loaded, broadcast via shfl;
// h gathers issued 8-deep with no interleaved uniform loads.

template <int MODE>
__global__ __launch_bounds__(256) void gather_pass(const ushort* __restrict__ h,
                                                   const int* __restrict__ row_ptr,
                                                   const int2* __restrict__ meta,
                                                   const float* __restrict__ dinv,
                                                   uint* __restrict__ aggb,
                                                   float* __restrict__ part_e) {
    int wid = threadIdx.x >> 6;
    int lane = threadIdx.x & 63;
    int d = blockIdx.x * 4 + wid;
    if (d >= N_NODES) return;
    const char* hb = (const char*)h;
    int lane4 = lane * 4;
    uint hdw = *(const uint*)(hb + (size_t)d * 256 + lane4);
    float hd0 = bf2f_lo(hdw), hd1 = bf2f_hi(hdw);
    float a0 = 0.f, a1 = 0.f;
    if (MODE & 1) { float di = dinv[d]; float w = di * di; a0 = w * hd0; a1 = w * hd1; }
    float ep = 0.f;
    int e0 = row_ptr[d], e1 = row_ptr[d + 1];

    for (int base = e0; base < e1; base += 64) {
        int cnt = min(64, e1 - base);
        int2 m = make_int2(0, 0);
        if (lane < cnt) m = meta[base + lane];
        int j = 0;
        for (; j + 7 < cnt; j += 8) {
            uint v[8], wp[8];
#pragma unroll
            for (int q = 0; q < 8; q++) {
                int so = __shfl(m.x, j + q);
                wp[q] = (uint)__shfl(m.y, j + q);
                v[q] = *(const uint*)(hb + (uint)(so + lane4));
            }
#pragma unroll
            for (int q = 0; q < 8; q++) {
                float x0 = bf2f_lo(v[q]), x1 = bf2f_hi(v[q]);
                if (MODE & 1) {
                    float w = bf2f_lo(wp[q]);
                    a0 += w * x0; a1 += w * x1;
                }
                if (MODE & 2) {
                    float ew = bf2f_hi(wp[q]);
                    float dx0 = x0 - hd0, dx1 = x1 - hd1;
                    ep += ew * (dx0 * dx0 + dx1 * dx1);
                }
            }
        }
        for (; j < cnt; j++) {
            int so = __shfl(m.x, j);
            uint wpk = (uint)__shfl(m.y, j);
            uint v = *(const uint*)(hb + (uint)(so + lane4));
            float x0 = bf2f_lo(v), x1 = bf2f_hi(v);
            if (MODE & 1) {
                float w = bf2f_lo(wpk);
                a0 += w * x0; a1 += w * x1;
            }
            if (MODE & 2) {
                float ew = bf2f_hi(wpk);
                float dx0 = x0 - hd0, dx1 = x1 - hd1;
                ep += ew * (dx0 * dx0 + dx1 * dx1);
            }
        }
    }

    if (MODE & 1) {
        uint pk = (uint)f2bf(a0) | ((uint)f2bf(a1) << 16);
        aggb[(size_t)d * 64 + lane] = pk;
    }
    if (MODE & 2) {
        for (int off = 32; off > 0; off >>= 1) ep += __shfl_down(ep, off);
        if (lane == 0) atomicAdd(&part_e[d & (NSLOT - 1)], 0.5f * ep);
    }
}

// ---------------- final reduce ----------------

__global__ __launch_bounds__(512) void finalize(const float* __restrict__ part,
                                                float* __restrict__ out) {
    int o = blockIdx.x;
    int t = threadIdx.x;
    float p = part[o * NSLOT + t];
    for (int off = 32; off > 0; off >>= 1) p += __shfl_down(p, off);
    __shared__ float sp[8];
    if ((t & 63) == 0) sp[t >> 6] = p;
    __syncthreads();
    if (t == 0) {
        float s = 0.f;
        for (int i = 0; i < 8; i++) s += sp[i];
        out[o] = s;
    }
}

// ---------------- launch ----------------

extern "C" void kernel_launch(void* const* d_in, const int* in_sizes, int n_in,
                              void* d_out, int out_size, void* d_ws, size_t ws_size,
                              hipStream_t stream) {
    const float* x      = (const float*)d_in[0];
    const int*   ei     = (const int*)d_in[1];
    const float* enc_w  = (const float*)d_in[2];
    const float* enc_b  = (const float*)d_in[3];
    const float* convw  = (const float*)d_in[4];
    const int* src = ei;
    const int* dst = ei + N_EDGES;
    float* out = (float*)d_out;

    size_t off = 0;
    auto alloc = [&](size_t bytes) {
        void* p = (char*)d_ws + off;
        off += (bytes + 255) & ~(size_t)255;
        return p;
    };
    ushort* h       = (ushort*)alloc((size_t)N_NODES * DIM * 2);   // bf16 features
    uint*   aggb    = (uint*)alloc((size_t)N_NODES * DIM * 2);     // bf16 aggregate
    ushort* wsb     = (ushort*)alloc((size_t)5 * DIM * DIM * 2);   // bf16 weights
    int*   deg_out  = (int*)alloc((size_t)N_NODES * 4);
    int*   deg_in   = (int*)alloc((size_t)N_NODES * 4);
    float* dinv     = (float*)alloc((size_t)N_NODES * 4);
    float2* np      = (float2*)alloc((size_t)N_NODES * 8);
    int*   row_ptr  = (int*)alloc((size_t)(N_NODES + 1) * 4);
    int*   cursor   = (int*)alloc((size_t)N_NODES * 4);
    int*   aux      = (int*)alloc((size_t)(SCAN_BLOCKS + 1) * 4);
    int2*  meta     = (int2*)alloc((size_t)N_EDGES * 8);
    float* part     = (float*)alloc((size_t)8 * NSLOT * 4);

    hipMemsetAsync(deg_out, 0, (size_t)N_NODES * 4, stream);
    hipMemsetAsync(deg_in, 0, (size_t)N_NODES * 4, stream);
    hipMemsetAsync(cursor, 0, (size_t)N_NODES * 4, stream);
    hipMemsetAsync(part, 0, (size_t)8 * NSLOT * 4, stream);

    int eb = (N_EDGES + 255) / 256;
    cvt_w<<<(5 * DIM * DIM + 255) / 256, 256, 0, stream>>>(enc_w, convw, wsb);
    count_deg<<<eb, 256, 0, stream>>>(src, dst, deg_out, deg_in);
    compute_nodeprops<<<(N_NODES + 255) / 256, 256, 0, stream>>>(deg_in, deg_out, dinv, np);
    scan1<<<SCAN_BLOCKS, 1024, 0, stream>>>(deg_in, row_ptr, aux);
    scan2<<<1, 64, 0, stream>>>(aux);
    scan3<<<SCAN_BLOCKS, 1024, 0, stream>>>(row_ptr, aux);
    fill_csr<<<eb, 256, 0, stream>>>(src, dst, row_ptr, cursor, dinv, np, meta);

    int gb = (N_NODES + 3) / 4;
    const int GB = 256;   // GEMM blocks (persistent waves)

    // encoder: h0 = x @ enc_w^T + enc_b
    gemm_mfma<true, false, false, true><<<GB, 256, 0, stream>>>(x, wsb, enc_b, h, nullptr);

    // layer 1: agg only
    gather_pass<1><<<gb, 256, 0, stream>>>(h, row_ptr, meta, dinv, aggb, nullptr);
    gemm_mfma<false, true, true, false><<<GB, 256, 0, stream>>>(aggb, wsb + DIM * DIM, nullptr,
                                                                h, part + 4 * NSLOT);
    // layers 2..4: fused agg(l) + energy(l-1)
    for (int l = 1; l < N_LAYERS; l++) {
        gather_pass<3><<<gb, 256, 0, stream>>>(h, row_ptr, meta, dinv, aggb,
                                               part + (l - 1) * NSLOT);
        gemm_mfma<false, true, true, false><<<GB, 256, 0, stream>>>(
            aggb, wsb + (size_t)(1 + l) * DIM * DIM, nullptr, h, part + (4 + l) * NSLOT);
    }
    // final: energy(4) only
    gather_pass<2><<<gb, 256, 0, stream>>>(h, row_ptr, meta, dinv, nullptr,
                                           part + 3 * NSLOT);
    finalize<<<8, NSLOT, 0, stream>>>(part, out);
}